// Round 4
// baseline (680.381 us; speedup 1.0000x reference)
//
#include <hip/hip_runtime.h>

#define NN 20000   // nodes per graph

typedef __attribute__((ext_vector_type(8))) __bf16 bf16x8;
typedef __attribute__((ext_vector_type(4))) float f32x4;

__device__ __forceinline__ unsigned short f2bf(float f) {
    unsigned u = __builtin_bit_cast(unsigned, f);
    u += 0x7fff + ((u >> 16) & 1);   // round-to-nearest-even
    return (unsigned short)(u >> 16);
}
__device__ __forceinline__ float bf2f(unsigned short h) {
    unsigned u = ((unsigned)h) << 16;
    return __builtin_bit_cast(float, u);
}

// ---------------- CSR build ----------------

__global__ void k_count(const int* __restrict__ dst, long dst_bs,
                        int* __restrict__ counts, long cnt_bs, int E) {
    int b = blockIdx.z;
    const int* d = dst + (size_t)b * dst_bs;
    int* c = counts + (size_t)b * cnt_bs;
    for (int e = blockIdx.x * blockDim.x + threadIdx.x; e < E; e += gridDim.x * blockDim.x)
        atomicAdd(&c[d[e]], 1);
}

__global__ void k_scan(const int* __restrict__ counts, long cnt_bs,
                       int* __restrict__ offs, long off_bs,
                       int* __restrict__ cursor, long cur_bs, int n) {
    int b = blockIdx.z;
    const int* cnt = counts + (size_t)b * cnt_bs;
    int* off = offs + (size_t)b * off_bs;
    int* cur = cursor + (size_t)b * cur_bs;
    __shared__ int sums[256];
    int t = threadIdx.x;
    int chunk = (n + 255) / 256;
    int lo = t * chunk;
    int hi = min(lo + chunk, n);
    int s = 0;
    for (int i = lo; i < hi; i++) s += cnt[i];
    sums[t] = s;
    __syncthreads();
    for (int d2 = 1; d2 < 256; d2 <<= 1) {
        int x = (t >= d2) ? sums[t - d2] : 0;
        __syncthreads();
        sums[t] += x;
        __syncthreads();
    }
    if (t == 255) off[n] = sums[255];
    int run = sums[t] - s;
    for (int i = lo; i < hi; i++) {
        int c = cnt[i];
        off[i] = run;
        cur[i] = run;
        run += c;
    }
}

__global__ void k_fill(const int* __restrict__ src, long src_bs,
                       const int* __restrict__ dst, long dst_bs,
                       int* __restrict__ cursor, long cur_bs,
                       int* __restrict__ elist, long el_bs, int E) {
    int b = blockIdx.z;
    const int* s = src + (size_t)b * src_bs;
    const int* d = dst + (size_t)b * dst_bs;
    int* cur = cursor + (size_t)b * cur_bs;
    int* el = elist + (size_t)b * el_bs;
    for (int e = blockIdx.x * blockDim.x + threadIdx.x; e < E; e += gridDim.x * blockDim.x) {
        int p = atomicAdd(&cur[d[e]], 1);
        el[p] = s[e];
    }
}

// ---------------- aggregation via L2-resident column strips ----------------
// grid = (ceil(N/8), 4 passes, nb batches). Pass p gathers cols [32p, 32p+32):
// per-pass source footprint = N*128B = 2.56 MB -> L2-resident per XCD.
// x-fastest dispatch order keeps one (batch,pass) strip hot at a time.

template <bool SPLIT>
__global__ void k_aggs(const float* __restrict__ feat, long feat_bs,
                       const int* __restrict__ offs, long off_bs,
                       const int* __restrict__ elist, long el_bs,
                       const float* __restrict__ bias,   // nullable
                       void* __restrict__ o1, void* __restrict__ o2,
                       long out_bs, int N) {
    int b = blockIdx.z, pass = blockIdx.y;
    int g = threadIdx.x >> 5;        // 8 half-wave node groups
    int lane = threadIdx.x & 31;
    int n = blockIdx.x * 8 + g;
    if (n >= N) return;
    int col = pass * 32 + lane;
    const float* fp = feat + (size_t)b * feat_bs + col;
    const int* off = offs + (size_t)b * off_bs;
    const int* el = elist + (size_t)b * el_bs;
    int lo = off[n], hi = off[n + 1];
    float s0 = 0.f, s1 = 0.f, s2 = 0.f, s3 = 0.f;
    int e = lo;
    for (; e + 4 <= hi; e += 4) {
        int i0 = __builtin_nontemporal_load(&el[e]);
        int i1 = __builtin_nontemporal_load(&el[e + 1]);
        int i2 = __builtin_nontemporal_load(&el[e + 2]);
        int i3 = __builtin_nontemporal_load(&el[e + 3]);
        s0 += fp[(size_t)i0 * 128];
        s1 += fp[(size_t)i1 * 128];
        s2 += fp[(size_t)i2 * 128];
        s3 += fp[(size_t)i3 * 128];
    }
    for (; e < hi; e++) s0 += fp[(size_t)__builtin_nontemporal_load(&el[e]) * 128];
    float r = (s0 + s1) + (s2 + s3);
    if (bias) r += bias[col];
    size_t oi = (size_t)b * out_bs + (size_t)n * 128 + col;
    if (SPLIT) {
        unsigned short h = f2bf(r);
        __builtin_nontemporal_store(h, (unsigned short*)o1 + oi);
        __builtin_nontemporal_store(f2bf(r - bf2f(h)), (unsigned short*)o2 + oi);
    } else {
        __builtin_nontemporal_store(r, (float*)o1 + oi);
    }
}

// ---------------- W prep: fp32 [K][N] -> transposed split bf16 [N][K] ----------------

__global__ void k_prep_w(const float* __restrict__ W1, const float* __restrict__ W2,
                         unsigned short* __restrict__ Wt1h, unsigned short* __restrict__ Wt1l,
                         unsigned short* __restrict__ Wt2h, unsigned short* __restrict__ Wt2l) {
    int i = blockIdx.x * 256 + threadIdx.x;
    if (i < 128 * 256) {
        {   // W1 [128][256] -> Wt1 [256][128]
            int k = i / 256, n = i % 256;
            float v = W1[i];
            unsigned short h = f2bf(v);
            Wt1h[n * 128 + k] = h;
            Wt1l[n * 128 + k] = f2bf(v - bf2f(h));
        }
        {   // W2 [256][128] -> Wt2 [128][256]
            int k = i / 128, n = i % 128;
            float v = W2[i];
            unsigned short h = f2bf(v);
            Wt2h[n * 256 + k] = h;
            Wt2l[n * 256 + k] = f2bf(v - bf2f(h));
        }
    }
}

// ---------------- split-bf16 MFMA GEMM, swapped operands ----------------
// C = (Ah+Al) @ (Wh+Wl) dropping Al*Wl. A row-major split-bf16 [M][K];
// W transposed split-bf16 [NC][K]. mfma(W_frag, A_frag, acc) puts the A-row in
// D's col=lane&15 and 4 consecutive output cols in the lane's 4 acc regs ->
// coalesced row-major stores. W fragments double-buffered (prefetch nf+1).
// Block = 256 thr = 4 waves, 16 rows/wave, BM=64.

template <int KSTEPS, int NFRAG, int KCHUNKS, bool RELU, bool SPLIT_OUT>
__launch_bounds__(256)
__global__ void k_lin(const unsigned short* __restrict__ Ah,
                      const unsigned short* __restrict__ Al, long A_bs,
                      const unsigned short* __restrict__ Wth,
                      const unsigned short* __restrict__ Wtl,
                      const float* __restrict__ bias,   // nullable
                      void* __restrict__ C1, void* __restrict__ C2, long C_bs, int M) {
    constexpr int K = KSTEPS * 32 * KCHUNKS;
    constexpr int NC = NFRAG * 16;
    constexpr int NACC = (KCHUNKS > 1) ? NFRAG : 1;
    int b = blockIdx.z;
    int w = threadIdx.x >> 6, lane = threadIdx.x & 63;
    int colg = lane & 15, kg = lane >> 4;
    int row = blockIdx.x * 64 + w * 16 + colg;
    bool rowok = row < M;
    int rowc = rowok ? row : M - 1;
    const unsigned short* pah = Ah + (size_t)b * A_bs + (size_t)rowc * K + kg * 8;
    const unsigned short* pal = Al + (size_t)b * A_bs + (size_t)rowc * K + kg * 8;

    bf16x8 fah[KSTEPS], fal[KSTEPS];
    bf16x8 whA[KSTEPS], wlA[KSTEPS], whB[KSTEPS], wlB[KSTEPS];
    f32x4 acc[NACC];
#pragma unroll
    for (int i = 0; i < NACC; i++) acc[i] = (f32x4){0.f, 0.f, 0.f, 0.f};

    auto loadW = [&](bf16x8* wh, bf16x8* wl, int nf, int kc) {
        const unsigned short* ph = Wth + (size_t)(nf * 16 + colg) * K + kc * (KSTEPS * 32) + kg * 8;
        const unsigned short* pl = Wtl + (size_t)(nf * 16 + colg) * K + kc * (KSTEPS * 32) + kg * 8;
#pragma unroll
        for (int ks = 0; ks < KSTEPS; ks++) {
            wh[ks] = *(const bf16x8*)(ph + ks * 32);
            wl[ks] = *(const bf16x8*)(pl + ks * 32);
        }
    };
    auto mm = [&](bf16x8* wh, bf16x8* wl, f32x4& a) {
#pragma unroll
        for (int ks = 0; ks < KSTEPS; ks++) {
            a = __builtin_amdgcn_mfma_f32_16x16x32_bf16(wh[ks], fah[ks], a, 0, 0, 0);
            a = __builtin_amdgcn_mfma_f32_16x16x32_bf16(wl[ks], fah[ks], a, 0, 0, 0);
            a = __builtin_amdgcn_mfma_f32_16x16x32_bf16(wh[ks], fal[ks], a, 0, 0, 0);
        }
    };
    auto epi = [&](f32x4 a, int nf) {
        if (!rowok) return;
        int c0 = nf * 16 + kg * 4;
        float v[4] = {a[0], a[1], a[2], a[3]};
        if (bias) {
            float4 bv = *(const float4*)&bias[c0];
            v[0] += bv.x; v[1] += bv.y; v[2] += bv.z; v[3] += bv.w;
        }
        if (RELU) {
#pragma unroll
            for (int j = 0; j < 4; j++) v[j] = fmaxf(v[j], 0.f);
        }
        size_t ci = (size_t)b * C_bs + (size_t)row * NC + c0;
        if (SPLIT_OUT) {
            union { unsigned short u[4]; uint2 q; } qh, ql;
#pragma unroll
            for (int j = 0; j < 4; j++) {
                qh.u[j] = f2bf(v[j]);
                ql.u[j] = f2bf(v[j] - bf2f(qh.u[j]));
            }
            *(uint2*)((unsigned short*)C1 + ci) = qh.q;
            *(uint2*)((unsigned short*)C2 + ci) = ql.q;
        } else {
            *(float4*)((float*)C1 + ci) = make_float4(v[0], v[1], v[2], v[3]);
        }
    };

#pragma unroll
    for (int kc = 0; kc < KCHUNKS; kc++) {
#pragma unroll
        for (int ks = 0; ks < KSTEPS; ks++) {
            fah[ks] = *(const bf16x8*)(pah + kc * (KSTEPS * 32) + ks * 32);
            fal[ks] = *(const bf16x8*)(pal + kc * (KSTEPS * 32) + ks * 32);
        }
        loadW(whA, wlA, 0, kc);
#pragma unroll
        for (int nf = 0; nf < NFRAG; nf += 2) {
            loadW(whB, wlB, nf + 1, kc);
            if constexpr (KCHUNKS > 1) {
                mm(whA, wlA, acc[nf]);
            } else {
                f32x4 a = (f32x4){0.f, 0.f, 0.f, 0.f};
                mm(whA, wlA, a);
                epi(a, nf);
            }
            if (nf + 2 < NFRAG) loadW(whA, wlA, nf + 2, kc);
            if constexpr (KCHUNKS > 1) {
                mm(whB, wlB, acc[nf + 1]);
            } else {
                f32x4 a = (f32x4){0.f, 0.f, 0.f, 0.f};
                mm(whB, wlB, a);
                epi(a, nf + 1);
            }
        }
    }
    if constexpr (KCHUNKS > 1) {
#pragma unroll
        for (int nf = 0; nf < NFRAG; nf++) epi(acc[nf], nf);
    }
}

// ---------------- host ----------------

extern "C" void kernel_launch(void* const* d_in, const int* in_sizes, int n_in,
                              void* d_out, int out_size, void* d_ws, size_t ws_size,
                              hipStream_t stream) {
    const float* features = (const float*)d_in[0];  // [B,N,128]
    const int* src = (const int*)d_in[1];           // [B,E]
    const int* dst = (const int*)d_in[2];           // [B,E]
    const float* W1 = (const float*)d_in[3];        // [128,256]
    const float* b1 = (const float*)d_in[4];        // [256]
    const float* W2 = (const float*)d_in[5];        // [256,128]
    const float* b2 = (const float*)d_in[6];        // [128]
    float* out = (float*)d_out;                     // [B,N,128]

    const int B = 4;
    const int N = NN;
    const int E = in_sizes[1] / B;

    auto need = [&](int nb) -> size_t {
        size_t f32b = (size_t)nb * N * 128 * sizeof(float);                 // H2
        size_t bf = ((size_t)nb * N * 128 * 2 + (size_t)nb * N * 256 * 2)   // A1 + H hi/lo
                    * sizeof(unsigned short);
        size_t wt = 4 * 32768 * sizeof(unsigned short);
        size_t ints = (size_t)nb * ((size_t)(N + 1) + N + E) * sizeof(int);
        return f32b + bf + wt + ints;
    };
    int nb = (ws_size >= need(4)) ? 4 : 1;
    int npass = B / nb;

    char* p = (char*)d_ws;
    float* H2 = (float*)p;           p += (size_t)nb * N * 128 * sizeof(float);
    unsigned short* A1h = (unsigned short*)p; p += (size_t)nb * N * 128 * sizeof(unsigned short);
    unsigned short* A1l = (unsigned short*)p; p += (size_t)nb * N * 128 * sizeof(unsigned short);
    unsigned short* Hh  = (unsigned short*)p; p += (size_t)nb * N * 256 * sizeof(unsigned short);
    unsigned short* Hl  = (unsigned short*)p; p += (size_t)nb * N * 256 * sizeof(unsigned short);
    unsigned short* Wt1h = (unsigned short*)p; p += 32768 * sizeof(unsigned short);
    unsigned short* Wt1l = (unsigned short*)p; p += 32768 * sizeof(unsigned short);
    unsigned short* Wt2h = (unsigned short*)p; p += 32768 * sizeof(unsigned short);
    unsigned short* Wt2l = (unsigned short*)p; p += 32768 * sizeof(unsigned short);
    int* offs = (int*)p;  p += (size_t)nb * (N + 1) * sizeof(int);
    int* curs = (int*)p;  p += (size_t)nb * N * sizeof(int);
    int* elist = (int*)p;

    k_prep_w<<<128, 256, 0, stream>>>(W1, W2, Wt1h, Wt1l, Wt2h, Wt2l);

    for (int pass = 0; pass < npass; pass++) {
        int b0 = pass * nb;
        const float* feat_p = features + (size_t)b0 * N * 128;
        const int* src_p = src + (size_t)b0 * E;
        const int* dst_p = dst + (size_t)b0 * E;
        float* out_p = out + (size_t)b0 * N * 128;

        hipMemsetAsync(curs, 0, (size_t)nb * N * sizeof(int), stream);

        dim3 gE((E + 255) / 256, 1, nb);
        k_count<<<gE, 256, 0, stream>>>(dst_p, E, curs, N, E);
        k_scan<<<dim3(1, 1, nb), 256, 0, stream>>>(curs, N, offs, N + 1, curs, N, N);
        k_fill<<<gE, 256, 0, stream>>>(src_p, E, dst_p, E, curs, N, elist, E, E);

        dim3 gAgg((N + 7) / 8, 4, nb);   // y = column-strip pass
        // conv1 aggregation -> split bf16: (A1h, A1l) = segsum(feat[src] -> dst)
        k_aggs<true><<<gAgg, 256, 0, stream>>>(feat_p, (long)N * 128, offs, N + 1,
                                               elist, E, nullptr, A1h, A1l, (long)N * 128, N);
        // conv1 linear + bias + relu -> split bf16: (Hh, Hl)
        k_lin<4, 16, 1, true, true><<<dim3((N + 63) / 64, 1, nb), 256, 0, stream>>>(
            A1h, A1l, (long)N * 128, Wt1h, Wt1l, b1, Hh, Hl, (long)N * 256, N);
        // conv2 linear (agg commutes): H2 = H @ W2, fp32
        k_lin<4, 8, 2, false, false><<<dim3((N + 63) / 64, 1, nb), 256, 0, stream>>>(
            Hh, Hl, (long)N * 256, Wt2h, Wt2l, nullptr, H2, nullptr, (long)N * 128, N);
        // conv2 aggregation + bias: out = segsum(H2[src] -> dst) + b2
        k_aggs<false><<<gAgg, 256, 0, stream>>>(H2, (long)N * 128, offs, N + 1,
                                                elist, E, b2, out_p, nullptr, (long)N * 128, N);
    }
}

// Round 5
// 454.846 us; speedup vs baseline: 1.4958x; 1.4958x over previous
//
#include <hip/hip_runtime.h>

#define NN 20000   // nodes per graph

typedef __attribute__((ext_vector_type(8))) __bf16 bf16x8;
typedef __attribute__((ext_vector_type(4))) float f32x4;

__device__ __forceinline__ unsigned short f2bf(float f) {
    unsigned u = __builtin_bit_cast(unsigned, f);
    u += 0x7fff + ((u >> 16) & 1);   // round-to-nearest-even
    return (unsigned short)(u >> 16);
}
__device__ __forceinline__ float bf2f(unsigned short h) {
    unsigned u = ((unsigned)h) << 16;
    return __builtin_bit_cast(float, u);
}

// ---------------- CSR build ----------------

__global__ void k_count(const int* __restrict__ dst, long dst_bs,
                        int* __restrict__ counts, long cnt_bs, int E) {
    int b = blockIdx.z;
    const int* d = dst + (size_t)b * dst_bs;
    int* c = counts + (size_t)b * cnt_bs;
    for (int e = blockIdx.x * blockDim.x + threadIdx.x; e < E; e += gridDim.x * blockDim.x)
        atomicAdd(&c[d[e]], 1);
}

__global__ void k_scan(const int* __restrict__ counts, long cnt_bs,
                       int* __restrict__ offs, long off_bs,
                       int* __restrict__ cursor, long cur_bs, int n) {
    int b = blockIdx.z;
    const int* cnt = counts + (size_t)b * cnt_bs;
    int* off = offs + (size_t)b * off_bs;
    int* cur = cursor + (size_t)b * cur_bs;
    __shared__ int sums[256];
    int t = threadIdx.x;
    int chunk = (n + 255) / 256;
    int lo = t * chunk;
    int hi = min(lo + chunk, n);
    int s = 0;
    for (int i = lo; i < hi; i++) s += cnt[i];
    sums[t] = s;
    __syncthreads();
    for (int d2 = 1; d2 < 256; d2 <<= 1) {
        int x = (t >= d2) ? sums[t - d2] : 0;
        __syncthreads();
        sums[t] += x;
        __syncthreads();
    }
    if (t == 255) off[n] = sums[255];
    int run = sums[t] - s;
    for (int i = lo; i < hi; i++) {
        int c = cnt[i];
        off[i] = run;
        cur[i] = run;
        run += c;
    }
}

__global__ void k_fill(const int* __restrict__ src, long src_bs,
                       const int* __restrict__ dst, long dst_bs,
                       int* __restrict__ cursor, long cur_bs,
                       int* __restrict__ elist, long el_bs, int E) {
    int b = blockIdx.z;
    const int* s = src + (size_t)b * src_bs;
    const int* d = dst + (size_t)b * dst_bs;
    int* cur = cursor + (size_t)b * cur_bs;
    int* el = elist + (size_t)b * el_bs;
    for (int e = blockIdx.x * blockDim.x + threadIdx.x; e < E; e += gridDim.x * blockDim.x) {
        int p = atomicAdd(&cur[d[e]], 1);
        el[p] = s[e];
    }
}

// ---------------- aggregation: 32-col strips, 8-lane groups, float4 + int4 el ----------------
// grid = (N/32, 4 passes, nb). Pass p gathers cols [32p,32p+32).
// 8 lanes * float4 = one 128 B row-strip; wave-instr covers 8 rows = 1024 B.
// el indices loaded as int4 (4 edges per instr per group).

template <bool SPLIT>
__global__ void k_aggs(const float* __restrict__ feat, long feat_bs,
                       const int* __restrict__ offs, long off_bs,
                       const int* __restrict__ elist, long el_bs,
                       const float* __restrict__ bias,   // nullable
                       void* __restrict__ o1, void* __restrict__ o2,
                       long out_bs, int N) {
    int b = blockIdx.z, pass = blockIdx.y;
    int g = threadIdx.x >> 3;        // 32 groups per 256-block
    int lane = threadIdx.x & 7;      // 8 lanes * float4 = 32 cols
    int n = blockIdx.x * 32 + g;
    if (n >= N) return;
    int col0 = pass * 32 + lane * 4;
    const float* fp = feat + (size_t)b * feat_bs + col0;
    const int* off = offs + (size_t)b * off_bs;
    const int* el = elist + (size_t)b * el_bs;
    int lo = off[n], hi = off[n + 1];
    float4 a0 = make_float4(0.f, 0.f, 0.f, 0.f);
    float4 a1 = make_float4(0.f, 0.f, 0.f, 0.f);
    float4 a2 = make_float4(0.f, 0.f, 0.f, 0.f);
    float4 a3 = make_float4(0.f, 0.f, 0.f, 0.f);
    int e = lo;
    // head: advance to 16 B alignment of el
    for (; e < hi && (e & 3); e++) {
        float4 v = *(const float4*)&fp[(size_t)el[e] * 128];
        a0.x += v.x; a0.y += v.y; a0.z += v.z; a0.w += v.w;
    }
    for (; e + 4 <= hi; e += 4) {
        int4 idx = *(const int4*)&el[e];
        float4 v0 = *(const float4*)&fp[(size_t)idx.x * 128];
        float4 v1 = *(const float4*)&fp[(size_t)idx.y * 128];
        float4 v2 = *(const float4*)&fp[(size_t)idx.z * 128];
        float4 v3 = *(const float4*)&fp[(size_t)idx.w * 128];
        a0.x += v0.x; a0.y += v0.y; a0.z += v0.z; a0.w += v0.w;
        a1.x += v1.x; a1.y += v1.y; a1.z += v1.z; a1.w += v1.w;
        a2.x += v2.x; a2.y += v2.y; a2.z += v2.z; a2.w += v2.w;
        a3.x += v3.x; a3.y += v3.y; a3.z += v3.z; a3.w += v3.w;
    }
    for (; e < hi; e++) {
        float4 v = *(const float4*)&fp[(size_t)el[e] * 128];
        a0.x += v.x; a0.y += v.y; a0.z += v.z; a0.w += v.w;
    }
    float4 r;
    r.x = (a0.x + a1.x) + (a2.x + a3.x);
    r.y = (a0.y + a1.y) + (a2.y + a3.y);
    r.z = (a0.z + a1.z) + (a2.z + a3.z);
    r.w = (a0.w + a1.w) + (a2.w + a3.w);
    if (bias) {
        float4 bv = *(const float4*)&bias[col0];
        r.x += bv.x; r.y += bv.y; r.z += bv.z; r.w += bv.w;
    }
    size_t oi = (size_t)b * out_bs + (size_t)n * 128 + col0;
    if (SPLIT) {
        union { unsigned short u[4]; uint2 q; } qh, ql;
        float f[4] = {r.x, r.y, r.z, r.w};
#pragma unroll
        for (int i = 0; i < 4; i++) {
            qh.u[i] = f2bf(f[i]);
            ql.u[i] = f2bf(f[i] - bf2f(qh.u[i]));
        }
        *(uint2*)((unsigned short*)o1 + oi) = qh.q;
        *(uint2*)((unsigned short*)o2 + oi) = ql.q;
    } else {
        *(float4*)((float*)o1 + oi) = r;
    }
}

// ---------------- W prep: fp32 [K][N] -> transposed split bf16 [N][K] ----------------

__global__ void k_prep_w(const float* __restrict__ W1, const float* __restrict__ W2,
                         unsigned short* __restrict__ Wt1h, unsigned short* __restrict__ Wt1l,
                         unsigned short* __restrict__ Wt2h, unsigned short* __restrict__ Wt2l) {
    int i = blockIdx.x * 256 + threadIdx.x;
    if (i < 128 * 256) {
        {   // W1 [128][256] -> Wt1 [256][128]
            int k = i / 256, n = i % 256;
            float v = W1[i];
            unsigned short h = f2bf(v);
            Wt1h[n * 128 + k] = h;
            Wt1l[n * 128 + k] = f2bf(v - bf2f(h));
        }
        {   // W2 [256][128] -> Wt2 [128][256]
            int k = i / 128, n = i % 128;
            float v = W2[i];
            unsigned short h = f2bf(v);
            Wt2h[n * 256 + k] = h;
            Wt2l[n * 256 + k] = f2bf(v - bf2f(h));
        }
    }
}

// ---------------- split-bf16 MFMA GEMM, swapped operands, MF=2 ----------------
// C = (Ah+Al) @ (Wh+Wl) dropping Al*Wl. A row-major split-bf16 [M][K];
// W transposed split-bf16 [NC][K]. mfma(W_frag, A_frag, acc): D col=lane&15 is
// the A-row, the lane's 4 acc regs are 4 consecutive output cols -> coalesced
// stores (validated round 4). MF=2 -> two independent MFMA chains per wave.
// Block = 256 thr = 4 waves * 32 rows = 128 rows. W double-buffered.
// KCHUNKS>1: persistent acc over K chunks (GEMM2, K=256).

template <int KSTEPS, int NFRAG, int KCHUNKS, bool RELU, bool SPLIT_OUT>
__launch_bounds__(256)
__global__ void k_lin(const unsigned short* __restrict__ Ah,
                      const unsigned short* __restrict__ Al, long A_bs,
                      const unsigned short* __restrict__ Wth,
                      const unsigned short* __restrict__ Wtl,
                      const float* __restrict__ bias,   // nullable
                      void* __restrict__ C1, void* __restrict__ C2, long C_bs, int M) {
    constexpr int K = KSTEPS * 32 * KCHUNKS;
    constexpr int NC = NFRAG * 16;
    int b = blockIdx.z;
    int w = threadIdx.x >> 6, lane = threadIdx.x & 63;
    int colg = lane & 15, kg = lane >> 4;
    int rbase = blockIdx.x * 128 + w * 32;
    int row0 = rbase + colg;
    int row1 = rbase + 16 + colg;
    bool ok0 = row0 < M, ok1 = row1 < M;
    int rc0 = ok0 ? row0 : M - 1;
    int rc1 = ok1 ? row1 : M - 1;
    const unsigned short* pah0 = Ah + (size_t)b * A_bs + (size_t)rc0 * K + kg * 8;
    const unsigned short* pal0 = Al + (size_t)b * A_bs + (size_t)rc0 * K + kg * 8;
    const unsigned short* pah1 = Ah + (size_t)b * A_bs + (size_t)rc1 * K + kg * 8;
    const unsigned short* pal1 = Al + (size_t)b * A_bs + (size_t)rc1 * K + kg * 8;

    bf16x8 fah[2][KSTEPS], fal[2][KSTEPS];
    bf16x8 whA[KSTEPS], wlA[KSTEPS], whB[KSTEPS], wlB[KSTEPS];
    constexpr int NACC = (KCHUNKS > 1) ? NFRAG : 2;   // [nf][mf] flattened
    f32x4 acc[NACC][2];
#pragma unroll
    for (int i = 0; i < NACC; i++) {
        acc[i][0] = (f32x4){0.f, 0.f, 0.f, 0.f};
        acc[i][1] = (f32x4){0.f, 0.f, 0.f, 0.f};
    }

    auto loadW = [&](bf16x8* wh, bf16x8* wl, int nf, int kc) {
        const unsigned short* ph = Wth + (size_t)(nf * 16 + colg) * K + kc * (KSTEPS * 32) + kg * 8;
        const unsigned short* pl = Wtl + (size_t)(nf * 16 + colg) * K + kc * (KSTEPS * 32) + kg * 8;
#pragma unroll
        for (int ks = 0; ks < KSTEPS; ks++) {
            wh[ks] = *(const bf16x8*)(ph + ks * 32);
            wl[ks] = *(const bf16x8*)(pl + ks * 32);
        }
    };
    // two independent chains (mf=0,1) interleaved
    auto mm = [&](bf16x8* wh, bf16x8* wl, f32x4& c0, f32x4& c1) {
#pragma unroll
        for (int ks = 0; ks < KSTEPS; ks++) {
            c0 = __builtin_amdgcn_mfma_f32_16x16x32_bf16(wh[ks], fah[0][ks], c0, 0, 0, 0);
            c1 = __builtin_amdgcn_mfma_f32_16x16x32_bf16(wh[ks], fah[1][ks], c1, 0, 0, 0);
            c0 = __builtin_amdgcn_mfma_f32_16x16x32_bf16(wl[ks], fah[0][ks], c0, 0, 0, 0);
            c1 = __builtin_amdgcn_mfma_f32_16x16x32_bf16(wl[ks], fah[1][ks], c1, 0, 0, 0);
            c0 = __builtin_amdgcn_mfma_f32_16x16x32_bf16(wh[ks], fal[0][ks], c0, 0, 0, 0);
            c1 = __builtin_amdgcn_mfma_f32_16x16x32_bf16(wh[ks], fal[1][ks], c1, 0, 0, 0);
        }
    };
    auto epi = [&](f32x4 a, int nf, int mf) {
        bool ok = mf ? ok1 : ok0;
        if (!ok) return;
        int row = mf ? row1 : row0;
        int c0 = nf * 16 + kg * 4;
        float v[4] = {a[0], a[1], a[2], a[3]};
        if (bias) {
            float4 bv = *(const float4*)&bias[c0];
            v[0] += bv.x; v[1] += bv.y; v[2] += bv.z; v[3] += bv.w;
        }
        if (RELU) {
#pragma unroll
            for (int j = 0; j < 4; j++) v[j] = fmaxf(v[j], 0.f);
        }
        size_t ci = (size_t)b * C_bs + (size_t)row * NC + c0;
        if (SPLIT_OUT) {
            union { unsigned short u[4]; uint2 q; } qh, ql;
#pragma unroll
            for (int j = 0; j < 4; j++) {
                qh.u[j] = f2bf(v[j]);
                ql.u[j] = f2bf(v[j] - bf2f(qh.u[j]));
            }
            *(uint2*)((unsigned short*)C1 + ci) = qh.q;
            *(uint2*)((unsigned short*)C2 + ci) = ql.q;
        } else {
            *(float4*)((float*)C1 + ci) = make_float4(v[0], v[1], v[2], v[3]);
        }
    };

#pragma unroll
    for (int kc = 0; kc < KCHUNKS; kc++) {
#pragma unroll
        for (int ks = 0; ks < KSTEPS; ks++) {
            fah[0][ks] = *(const bf16x8*)(pah0 + kc * (KSTEPS * 32) + ks * 32);
            fal[0][ks] = *(const bf16x8*)(pal0 + kc * (KSTEPS * 32) + ks * 32);
            fah[1][ks] = *(const bf16x8*)(pah1 + kc * (KSTEPS * 32) + ks * 32);
            fal[1][ks] = *(const bf16x8*)(pal1 + kc * (KSTEPS * 32) + ks * 32);
        }
        loadW(whA, wlA, 0, kc);
#pragma unroll
        for (int nf = 0; nf < NFRAG; nf += 2) {
            loadW(whB, wlB, nf + 1, kc);
            if constexpr (KCHUNKS > 1) {
                mm(whA, wlA, acc[nf][0], acc[nf][1]);
            } else {
                f32x4 a0 = (f32x4){0.f, 0.f, 0.f, 0.f};
                f32x4 a1 = (f32x4){0.f, 0.f, 0.f, 0.f};
                mm(whA, wlA, a0, a1);
                epi(a0, nf, 0);
                epi(a1, nf, 1);
            }
            if (nf + 2 < NFRAG) loadW(whA, wlA, nf + 2, kc);
            if constexpr (KCHUNKS > 1) {
                mm(whB, wlB, acc[nf + 1][0], acc[nf + 1][1]);
            } else {
                f32x4 a0 = (f32x4){0.f, 0.f, 0.f, 0.f};
                f32x4 a1 = (f32x4){0.f, 0.f, 0.f, 0.f};
                mm(whB, wlB, a0, a1);
                epi(a0, nf + 1, 0);
                epi(a1, nf + 1, 1);
            }
        }
    }
    if constexpr (KCHUNKS > 1) {
#pragma unroll
        for (int nf = 0; nf < NFRAG; nf++) {
            epi(acc[nf][0], nf, 0);
            epi(acc[nf][1], nf, 1);
        }
    }
}

// ---------------- host ----------------

extern "C" void kernel_launch(void* const* d_in, const int* in_sizes, int n_in,
                              void* d_out, int out_size, void* d_ws, size_t ws_size,
                              hipStream_t stream) {
    const float* features = (const float*)d_in[0];  // [B,N,128]
    const int* src = (const int*)d_in[1];           // [B,E]
    const int* dst = (const int*)d_in[2];           // [B,E]
    const float* W1 = (const float*)d_in[3];        // [128,256]
    const float* b1 = (const float*)d_in[4];        // [256]
    const float* W2 = (const float*)d_in[5];        // [256,128]
    const float* b2 = (const float*)d_in[6];        // [128]
    float* out = (float*)d_out;                     // [B,N,128]

    const int B = 4;
    const int N = NN;
    const int E = in_sizes[1] / B;

    auto need = [&](int nb) -> size_t {
        size_t f32b = (size_t)nb * N * 128 * sizeof(float);                 // H2
        size_t bf = ((size_t)nb * N * 128 * 2 + (size_t)nb * N * 256 * 2)   // A1 + H hi/lo
                    * sizeof(unsigned short);
        size_t wt = 4 * 32768 * sizeof(unsigned short);
        size_t ints = (size_t)nb * ((size_t)(N + 1) + N + E) * sizeof(int);
        return f32b + bf + wt + ints;
    };
    int nb = (ws_size >= need(4)) ? 4 : 1;
    int npass = B / nb;

    char* p = (char*)d_ws;
    float* H2 = (float*)p;           p += (size_t)nb * N * 128 * sizeof(float);
    unsigned short* A1h = (unsigned short*)p; p += (size_t)nb * N * 128 * sizeof(unsigned short);
    unsigned short* A1l = (unsigned short*)p; p += (size_t)nb * N * 128 * sizeof(unsigned short);
    unsigned short* Hh  = (unsigned short*)p; p += (size_t)nb * N * 256 * sizeof(unsigned short);
    unsigned short* Hl  = (unsigned short*)p; p += (size_t)nb * N * 256 * sizeof(unsigned short);
    unsigned short* Wt1h = (unsigned short*)p; p += 32768 * sizeof(unsigned short);
    unsigned short* Wt1l = (unsigned short*)p; p += 32768 * sizeof(unsigned short);
    unsigned short* Wt2h = (unsigned short*)p; p += 32768 * sizeof(unsigned short);
    unsigned short* Wt2l = (unsigned short*)p; p += 32768 * sizeof(unsigned short);
    int* offs = (int*)p;  p += (size_t)nb * (N + 1) * sizeof(int);
    int* curs = (int*)p;  p += (size_t)nb * N * sizeof(int);
    int* elist = (int*)p;

    k_prep_w<<<128, 256, 0, stream>>>(W1, W2, Wt1h, Wt1l, Wt2h, Wt2l);

    for (int pass = 0; pass < npass; pass++) {
        int b0 = pass * nb;
        const float* feat_p = features + (size_t)b0 * N * 128;
        const int* src_p = src + (size_t)b0 * E;
        const int* dst_p = dst + (size_t)b0 * E;
        float* out_p = out + (size_t)b0 * N * 128;

        hipMemsetAsync(curs, 0, (size_t)nb * N * sizeof(int), stream);

        dim3 gE((E + 255) / 256, 1, nb);
        k_count<<<gE, 256, 0, stream>>>(dst_p, E, curs, N, E);
        k_scan<<<dim3(1, 1, nb), 256, 0, stream>>>(curs, N, offs, N + 1, curs, N, N);
        k_fill<<<gE, 256, 0, stream>>>(src_p, E, dst_p, E, curs, N, elist, E, E);

        dim3 gAgg((N + 31) / 32, 4, nb);   // y = column-strip pass
        // conv1 aggregation -> split bf16: (A1h, A1l) = segsum(feat[src] -> dst)
        k_aggs<true><<<gAgg, 256, 0, stream>>>(feat_p, (long)N * 128, offs, N + 1,
                                               elist, E, nullptr, A1h, A1l, (long)N * 128, N);
        // conv1 linear + bias + relu -> split bf16: (Hh, Hl)
        k_lin<4, 16, 1, true, true><<<dim3((N + 127) / 128, 1, nb), 256, 0, stream>>>(
            A1h, A1l, (long)N * 128, Wt1h, Wt1l, b1, Hh, Hl, (long)N * 256, N);
        // conv2 linear (agg commutes): H2 = H @ W2, fp32
        k_lin<4, 8, 2, false, false><<<dim3((N + 127) / 128, 1, nb), 256, 0, stream>>>(
            Hh, Hl, (long)N * 256, Wt2h, Wt2l, nullptr, H2, nullptr, (long)N * 128, N);
        // conv2 aggregation + bias: out = segsum(H2[src] -> dst) + b2
        k_aggs<false><<<gAgg, 256, 0, stream>>>(H2, (long)N * 128, offs, N + 1,
                                                elist, E, b2, out_p, nullptr, (long)N * 128, N);
    }
}